// Round 1
// baseline (70.996 us; speedup 1.0000x reference)
//
#include <hip/hip_runtime.h>
#include <math.h>

#define M_BATCH 8
#define NC 1024
#define NTGT 512
#define G_DIM 129
#define NG (G_DIM * G_DIM)        // 16641
#define N_OUT (G_DIM * 3)         // 387
#define TM 16                     // ix per block
#define TIY 16                    // iy per block
#define KCH 256
#define NKCH (NC / KCH)           // 4
#define LDA 264                   // padded LDS row stride (halves); 528B % 128 = 16 -> bank spread
#define ABYTES (TM * LDA * 2)     // 8448
#define BUFBYTES (2 * ABYTES + 1024)  // wx + wy + ye(512B) + yo(512B) = 17920
#define GT 9                      // tiles per dim (9*16=144 >= 129)

typedef __attribute__((ext_vector_type(8))) _Float16 half8;
typedef __attribute__((ext_vector_type(2))) _Float16 half2v;
typedef __attribute__((ext_vector_type(4))) float floatx4;

#if defined(__has_builtin)
#if __has_builtin(__builtin_amdgcn_exp2f)
#define FAST_EXP2(x) __builtin_amdgcn_exp2f(x)
#endif
#endif
#ifndef FAST_EXP2
#define FAST_EXP2(x) exp2f(x)
#endif

// ---- Kernel A: per-m minmax of concat(xc, xt) -> mids in workspace ----
// 8 blocks x 256 threads; shuffle-reduce (no barrier tree).
__global__ __launch_bounds__(256) void minmax_kernel(
        const float* __restrict__ xc, const float* __restrict__ xt,
        float* __restrict__ ws) {
    const int m = blockIdx.x;
    const int tid = threadIdx.x;
    float mn0 = 1e30f, mx0 = -1e30f, mn1 = 1e30f, mx1 = -1e30f;
    const float2* pc = (const float2*)(xc + m * NC * 2);
    for (int i = tid; i < NC; i += 256) {
        float2 p = pc[i];
        mn0 = fminf(mn0, p.x); mx0 = fmaxf(mx0, p.x);
        mn1 = fminf(mn1, p.y); mx1 = fmaxf(mx1, p.y);
    }
    const float2* pt = (const float2*)(xt + m * NTGT * 2);
    for (int i = tid; i < NTGT; i += 256) {
        float2 p = pt[i];
        mn0 = fminf(mn0, p.x); mx0 = fmaxf(mx0, p.x);
        mn1 = fminf(mn1, p.y); mx1 = fmaxf(mx1, p.y);
    }
#pragma unroll
    for (int s = 1; s < 64; s <<= 1) {
        mn0 = fminf(mn0, __shfl_xor(mn0, s));
        mx0 = fmaxf(mx0, __shfl_xor(mx0, s));
        mn1 = fminf(mn1, __shfl_xor(mn1, s));
        mx1 = fmaxf(mx1, __shfl_xor(mx1, s));
    }
    __shared__ float4 red[4];
    if ((tid & 63) == 0) red[tid >> 6] = make_float4(mn0, mx0, mn1, mx1);
    __syncthreads();
    if (tid == 0) {
        float4 a = red[0];
#pragma unroll
        for (int w2 = 1; w2 < 4; ++w2) {
            float4 b = red[w2];
            a.x = fminf(a.x, b.x); a.y = fmaxf(a.y, b.y);
            a.z = fminf(a.z, b.z); a.w = fmaxf(a.w, b.w);
        }
        ws[2 * m]     = 0.5f * (a.x + a.y);
        ws[2 * m + 1] = 0.5f * (a.z + a.w);
    }
}

// ---- Kernel B: 16x16 output tile per block, 256 threads = 4 waves ----
// 4 waves K-split the 256-wide chunk (wave w does ksteps 2w, 2w+1).
// Per chunk stage wx(16x256), wy(16x256), ye/yo(256) in LDS, double-buffered,
// 1 barrier per chunk. Cross-wave reduce at the end.
__global__ __launch_bounds__(256) void fused_kernel(
        const float* __restrict__ xc, const float* __restrict__ yc,
        const float* __restrict__ lsp, const float* __restrict__ ws,
        float* __restrict__ out_grid, float* __restrict__ out_z) {
    const int tid = threadIdx.x;
    const int iyt = blockIdx.x;        // 0..8
    const int mt = blockIdx.y;         // 0..8
    const int m  = blockIdx.z;

    __shared__ __align__(16) char lds_raw[2 * BUFBYTES];   // 35840 B -> 4 blocks/CU

    const float mid0 = ws[2 * m];
    const float mid1 = ws[2 * m + 1];

    const float Kc = 0.84932180028801904272f;  // sqrt(0.5*log2(e))
    const float ls0 = 1e-5f + log1pf(expf(lsp[0]));
    const float ls1 = 1e-5f + log1pf(expf(lsp[1]));
    const float s0 = Kc / ls0, s1 = Kc / ls1;
    const float inv_ppu = 1.0f / 64.0f;

    // ---- x_grid rows of this mt (iyt==0 blocks) ----
    if (iyt == 0) {
        const int r0 = mt * TM;
        const int nrows = min(TM, G_DIM - r0);
        float2* og = (float2*)out_grid + (size_t)m * NG;
        for (int g = tid; g < nrows * G_DIM; g += 256) {
            const int r = g / G_DIM;
            const int iyy = g - r * G_DIM;
            const int ixg = r0 + r;
            og[(size_t)ixg * G_DIM + iyy] =
                make_float2(mid0 + (float)(ixg - 64) * inv_ppu,
                            mid1 + (float)(iyy - 64) * inv_ppu);
        }
    }

    // ---- staging setup ----
    const int cpair = tid & 127;          // float4 (2-point) index within chunk
    const int rbase = tid >> 7;           // 0/1: even/odd rows
    const int c2 = cpair * 2;             // half-pair column
    const float4* xc4 = (const float4*)(xc + m * NC * 2);
    const float4* yc4 = (const float4*)(yc + m * NC * 2);
    const float gxs_base = (mid0 + (float)(mt * TM - 64) * inv_ppu) * s0;
    const float gys_base = (mid1 + (float)(iyt * TIY - 64) * inv_ppu) * s1;
    const float gstep_x = inv_ppu * s0;
    const float gstep_y = inv_ppu * s1;

    const int w = tid >> 6;               // wave = K-group 0..3
    const int lane = tid & 63;
    const int ln = lane & 15;
    const int q = lane >> 4;

    floatx4 acc0 = {0.f, 0.f, 0.f, 0.f};
    floatx4 acc1 = {0.f, 0.f, 0.f, 0.f};
    floatx4 acc2 = {0.f, 0.f, 0.f, 0.f};

    auto stage = [&](int kc, int buf) {
        const int cp = kc * 128 + cpair;
        const float4 xq = xc4[cp];
        const float4 yq = yc4[cp];
        const float cx0 = xq.x * s0, cx1 = xq.z * s0;
        const float cy0 = xq.y * s1, cy1 = xq.w * s1;
        _Float16* Ab  = (_Float16*)(lds_raw + buf * BUFBYTES);
        _Float16* Wyb = (_Float16*)(lds_raw + buf * BUFBYTES + ABYTES);
        _Float16* yeb = (_Float16*)(lds_raw + buf * BUFBYTES + 2 * ABYTES);
        _Float16* yob = yeb + KCH;
#pragma unroll
        for (int i = 0; i < 8; ++i) {
            const int r = rbase + 2 * i;
            const float gxs = gxs_base + (float)r * gstep_x;
            const float dx0 = gxs - cx0;
            const float dx1 = gxs - cx1;
            *(half2v*)&Ab[r * LDA + c2] =
                (half2v){(_Float16)FAST_EXP2(-(dx0 * dx0)),
                         (_Float16)FAST_EXP2(-(dx1 * dx1))};
            const float gys = gys_base + (float)r * gstep_y;
            const float dy0 = gys - cy0;
            const float dy1 = gys - cy1;
            *(half2v*)&Wyb[r * LDA + c2] =
                (half2v){(_Float16)FAST_EXP2(-(dy0 * dy0)),
                         (_Float16)FAST_EXP2(-(dy1 * dy1))};
        }
        if (tid < 128) {
            *(half2v*)&yeb[c2] = (half2v){(_Float16)yq.x, (_Float16)yq.z};
            *(half2v*)&yob[c2] = (half2v){(_Float16)yq.y, (_Float16)yq.w};
        }
    };

    stage(0, 0);
    __syncthreads();

    for (int kc = 0; kc < NKCH; ++kc) {
        const int buf = kc & 1;
        const _Float16* Ab  = (const _Float16*)(lds_raw + buf * BUFBYTES);
        const _Float16* Wyb = (const _Float16*)(lds_raw + buf * BUFBYTES + ABYTES);
        const _Float16* yeb = (const _Float16*)(lds_raw + buf * BUFBYTES + 2 * ABYTES);
#pragma unroll
        for (int kk = 0; kk < 2; ++kk) {
            const int off = (w * 2 + kk) * 32 + q * 8;
            half8 a  = *(const half8*)&Ab[ln * LDA + off];
            half8 wy = *(const half8*)&Wyb[ln * LDA + off];
            half8 ye = *(const half8*)&yeb[off];
            half8 yo = *(const half8*)&yeb[KCH + off];
            acc2 = __builtin_amdgcn_mfma_f32_16x16x32_f16(a, wy, acc2, 0, 0, 0);
            acc0 = __builtin_amdgcn_mfma_f32_16x16x32_f16(a, wy * ye, acc0, 0, 0, 0);
            acc1 = __builtin_amdgcn_mfma_f32_16x16x32_f16(a, wy * yo, acc1, 0, 0, 0);
        }
        if (kc + 1 < NKCH) stage(kc + 1, buf ^ 1);
        __syncthreads();
    }

    // ---- cross-wave reduction: waves 1..3 write, wave 0 adds + stores ----
    floatx4* cs = (floatx4*)lds_raw;       // [3 waves][3 ch][64 lanes] = 9216 B
    if (w > 0) {
        cs[((w - 1) * 3 + 0) * 64 + lane] = acc0;
        cs[((w - 1) * 3 + 1) * 64 + lane] = acc1;
        cs[((w - 1) * 3 + 2) * 64 + lane] = acc2;
    }
    __syncthreads();
    if (w == 0) {
#pragma unroll
        for (int ww = 0; ww < 3; ++ww) {
            acc0 += cs[(ww * 3 + 0) * 64 + lane];
            acc1 += cs[(ww * 3 + 1) * 64 + lane];
            acc2 += cs[(ww * 3 + 2) * 64 + lane];
        }
        const int iyg = iyt * TIY + ln;
        if (iyg < G_DIM) {
            float* oz = out_z + (size_t)m * NG * 3 + (size_t)iyg * 3;
            const int ixb = mt * TM + q * 4;
#pragma unroll
            for (int rr = 0; rr < 4; ++rr) {
                const int ixg = ixb + rr;
                if (ixg < G_DIM) {
                    float* p = oz + (size_t)ixg * N_OUT;
                    p[0] = acc0[rr];
                    p[1] = acc1[rr];
                    p[2] = acc2[rr];
                }
            }
        }
    }
}

extern "C" void kernel_launch(void* const* d_in, const int* in_sizes, int n_in,
                              void* d_out, int out_size, void* d_ws, size_t ws_size,
                              hipStream_t stream) {
    const float* xc  = (const float*)d_in[0];
    const float* yc  = (const float*)d_in[1];
    const float* xt  = (const float*)d_in[2];
    const float* lsp = (const float*)d_in[3];

    float* out_grid = (float*)d_out;
    float* out_z = out_grid + (size_t)M_BATCH * NG * 2;
    float* ws = (float*)d_ws;   // 16 floats: (mid0, mid1) per m

    minmax_kernel<<<dim3(M_BATCH), 256, 0, stream>>>(xc, xt, ws);

    dim3 grid(GT, GT, M_BATCH);   // (9, 9, 8) = 648 blocks x 256 threads
    fused_kernel<<<grid, 256, 0, stream>>>(xc, yc, lsp, ws, out_grid, out_z);
}

// Round 2
// 67.767 us; speedup vs baseline: 1.0477x; 1.0477x over previous
//
#include <hip/hip_runtime.h>
#include <math.h>

#define M_BATCH 8
#define NC 1024
#define NTGT 512
#define G_DIM 129
#define NG (G_DIM * G_DIM)        // 16641
#define N_OUT (G_DIM * 3)         // 387
#define TM 16                     // ix per block
#define TIY 16                    // iy per block
#define KCH 256
#define NKCH (NC / KCH)           // 4
#define LDA 264                   // padded LDS row stride (halves); 528B % 128 = 16 -> bank spread
#define ABYTES (TM * LDA * 2)     // 8448
#define BUFBYTES (2 * ABYTES + 1024)  // wx + wy + ye(512B) + yo(512B) = 17920
#define GT 9                      // tiles per dim (9*16=144 >= 129)

typedef __attribute__((ext_vector_type(8))) _Float16 half8;
typedef __attribute__((ext_vector_type(2))) _Float16 half2v;
typedef __attribute__((ext_vector_type(4))) float floatx4;

#if defined(__has_builtin)
#if __has_builtin(__builtin_amdgcn_exp2f)
#define FAST_EXP2(x) __builtin_amdgcn_exp2f(x)
#endif
#endif
#ifndef FAST_EXP2
#define FAST_EXP2(x) exp2f(x)
#endif

// Single launch. 16x16 output tile per block, 256 threads = 4 waves.
// Per-block inline minmax via wave shuffle butterfly (1 barrier, no tree).
// 4 waves K-split the 256-wide chunk; double-buffered LDS staging,
// 1 barrier per chunk; cross-wave reduce at the end.
__global__ __launch_bounds__(256) void fused_kernel(
        const float* __restrict__ xc, const float* __restrict__ yc,
        const float* __restrict__ xt, const float* __restrict__ lsp,
        float* __restrict__ out_grid, float* __restrict__ out_z) {
    const int tid = threadIdx.x;
    const int iyt = blockIdx.x;        // 0..8
    const int mt = blockIdx.y;         // 0..8
    const int m  = blockIdx.z;

    __shared__ __align__(16) char lds_raw[2 * BUFBYTES];   // 35840 B -> 4 blocks/CU
    __shared__ float4 red[4];

    // ---- Phase 1: minmax over concat(xc[m], xt[m]) — shuffle butterfly ----
    float mn0 = 1e30f, mx0 = -1e30f, mn1 = 1e30f, mx1 = -1e30f;
    {
        const float2* pc = (const float2*)(xc + m * NC * 2);
#pragma unroll
        for (int i = 0; i < 4; ++i) {
            float2 p = pc[tid + 256 * i];
            mn0 = fminf(mn0, p.x); mx0 = fmaxf(mx0, p.x);
            mn1 = fminf(mn1, p.y); mx1 = fmaxf(mx1, p.y);
        }
        const float2* pt = (const float2*)(xt + m * NTGT * 2);
#pragma unroll
        for (int i = 0; i < 2; ++i) {
            float2 p = pt[tid + 256 * i];
            mn0 = fminf(mn0, p.x); mx0 = fmaxf(mx0, p.x);
            mn1 = fminf(mn1, p.y); mx1 = fmaxf(mx1, p.y);
        }
#pragma unroll
        for (int s = 1; s < 64; s <<= 1) {
            mn0 = fminf(mn0, __shfl_xor(mn0, s));
            mx0 = fmaxf(mx0, __shfl_xor(mx0, s));
            mn1 = fminf(mn1, __shfl_xor(mn1, s));
            mx1 = fmaxf(mx1, __shfl_xor(mx1, s));
        }
        if ((tid & 63) == 0) red[tid >> 6] = make_float4(mn0, mx0, mn1, mx1);
    }
    __syncthreads();
    float4 rv = red[0];
    {
#pragma unroll
        for (int ww = 1; ww < 4; ++ww) {
            float4 b = red[ww];
            rv.x = fminf(rv.x, b.x); rv.y = fmaxf(rv.y, b.y);
            rv.z = fminf(rv.z, b.z); rv.w = fmaxf(rv.w, b.w);
        }
    }
    const float mid0 = 0.5f * (rv.x + rv.y);
    const float mid1 = 0.5f * (rv.z + rv.w);

    const float Kc = 0.84932180028801904272f;  // sqrt(0.5*log2(e))
    const float ls0 = 1e-5f + log1pf(expf(lsp[0]));
    const float ls1 = 1e-5f + log1pf(expf(lsp[1]));
    const float s0 = Kc / ls0, s1 = Kc / ls1;
    const float inv_ppu = 1.0f / 64.0f;

    // ---- x_grid rows of this mt (iyt==0 blocks) ----
    if (iyt == 0) {
        const int r0 = mt * TM;
        const int nrows = min(TM, G_DIM - r0);
        float2* og = (float2*)out_grid + (size_t)m * NG;
        for (int g = tid; g < nrows * G_DIM; g += 256) {
            const int r = g / G_DIM;
            const int iyy = g - r * G_DIM;
            const int ixg = r0 + r;
            og[(size_t)ixg * G_DIM + iyy] =
                make_float2(mid0 + (float)(ixg - 64) * inv_ppu,
                            mid1 + (float)(iyy - 64) * inv_ppu);
        }
    }

    // ---- staging setup ----
    const int cpair = tid & 127;          // float4 (2-point) index within chunk
    const int rbase = tid >> 7;           // 0/1: even/odd rows
    const int c2 = cpair * 2;             // half-pair column
    const float4* xc4 = (const float4*)(xc + m * NC * 2);
    const float4* yc4 = (const float4*)(yc + m * NC * 2);
    const float gxs_base = (mid0 + (float)(mt * TM - 64) * inv_ppu) * s0;
    const float gys_base = (mid1 + (float)(iyt * TIY - 64) * inv_ppu) * s1;
    const float gstep_x = inv_ppu * s0;
    const float gstep_y = inv_ppu * s1;

    const int w = tid >> 6;               // wave = K-group 0..3
    const int lane = tid & 63;
    const int ln = lane & 15;
    const int q = lane >> 4;

    floatx4 acc0 = {0.f, 0.f, 0.f, 0.f};
    floatx4 acc1 = {0.f, 0.f, 0.f, 0.f};
    floatx4 acc2 = {0.f, 0.f, 0.f, 0.f};

    auto stage = [&](int kc, int buf) {
        const int cp = kc * 128 + cpair;
        const float4 xq = xc4[cp];
        const float4 yq = yc4[cp];
        const float cx0 = xq.x * s0, cx1 = xq.z * s0;
        const float cy0 = xq.y * s1, cy1 = xq.w * s1;
        _Float16* Ab  = (_Float16*)(lds_raw + buf * BUFBYTES);
        _Float16* Wyb = (_Float16*)(lds_raw + buf * BUFBYTES + ABYTES);
        _Float16* yeb = (_Float16*)(lds_raw + buf * BUFBYTES + 2 * ABYTES);
        _Float16* yob = yeb + KCH;
#pragma unroll
        for (int i = 0; i < 8; ++i) {
            const int r = rbase + 2 * i;
            const float gxs = gxs_base + (float)r * gstep_x;
            const float dx0 = gxs - cx0;
            const float dx1 = gxs - cx1;
            *(half2v*)&Ab[r * LDA + c2] =
                (half2v){(_Float16)FAST_EXP2(-(dx0 * dx0)),
                         (_Float16)FAST_EXP2(-(dx1 * dx1))};
            const float gys = gys_base + (float)r * gstep_y;
            const float dy0 = gys - cy0;
            const float dy1 = gys - cy1;
            *(half2v*)&Wyb[r * LDA + c2] =
                (half2v){(_Float16)FAST_EXP2(-(dy0 * dy0)),
                         (_Float16)FAST_EXP2(-(dy1 * dy1))};
        }
        if (tid < 128) {
            *(half2v*)&yeb[c2] = (half2v){(_Float16)yq.x, (_Float16)yq.z};
            *(half2v*)&yob[c2] = (half2v){(_Float16)yq.y, (_Float16)yq.w};
        }
    };

    stage(0, 0);
    __syncthreads();

    for (int kc = 0; kc < NKCH; ++kc) {
        const int buf = kc & 1;
        const _Float16* Ab  = (const _Float16*)(lds_raw + buf * BUFBYTES);
        const _Float16* Wyb = (const _Float16*)(lds_raw + buf * BUFBYTES + ABYTES);
        const _Float16* yeb = (const _Float16*)(lds_raw + buf * BUFBYTES + 2 * ABYTES);
#pragma unroll
        for (int kk = 0; kk < 2; ++kk) {
            const int off = (w * 2 + kk) * 32 + q * 8;
            half8 a  = *(const half8*)&Ab[ln * LDA + off];
            half8 wy = *(const half8*)&Wyb[ln * LDA + off];
            half8 ye = *(const half8*)&yeb[off];
            half8 yo = *(const half8*)&yeb[KCH + off];
            acc2 = __builtin_amdgcn_mfma_f32_16x16x32_f16(a, wy, acc2, 0, 0, 0);
            acc0 = __builtin_amdgcn_mfma_f32_16x16x32_f16(a, wy * ye, acc0, 0, 0, 0);
            acc1 = __builtin_amdgcn_mfma_f32_16x16x32_f16(a, wy * yo, acc1, 0, 0, 0);
        }
        if (kc + 1 < NKCH) stage(kc + 1, buf ^ 1);
        __syncthreads();
    }

    // ---- cross-wave reduction: waves 1..3 write, wave 0 adds + stores ----
    floatx4* cs = (floatx4*)lds_raw;       // [3 waves][3 ch][64 lanes] = 9216 B
    if (w > 0) {
        cs[((w - 1) * 3 + 0) * 64 + lane] = acc0;
        cs[((w - 1) * 3 + 1) * 64 + lane] = acc1;
        cs[((w - 1) * 3 + 2) * 64 + lane] = acc2;
    }
    __syncthreads();
    if (w == 0) {
#pragma unroll
        for (int ww = 0; ww < 3; ++ww) {
            acc0 += cs[(ww * 3 + 0) * 64 + lane];
            acc1 += cs[(ww * 3 + 1) * 64 + lane];
            acc2 += cs[(ww * 3 + 2) * 64 + lane];
        }
        const int iyg = iyt * TIY + ln;
        if (iyg < G_DIM) {
            float* oz = out_z + (size_t)m * NG * 3 + (size_t)iyg * 3;
            const int ixb = mt * TM + q * 4;
#pragma unroll
            for (int rr = 0; rr < 4; ++rr) {
                const int ixg = ixb + rr;
                if (ixg < G_DIM) {
                    float* p = oz + (size_t)ixg * N_OUT;
                    p[0] = acc0[rr];
                    p[1] = acc1[rr];
                    p[2] = acc2[rr];
                }
            }
        }
    }
}

extern "C" void kernel_launch(void* const* d_in, const int* in_sizes, int n_in,
                              void* d_out, int out_size, void* d_ws, size_t ws_size,
                              hipStream_t stream) {
    const float* xc  = (const float*)d_in[0];
    const float* yc  = (const float*)d_in[1];
    const float* xt  = (const float*)d_in[2];
    const float* lsp = (const float*)d_in[3];

    float* out_grid = (float*)d_out;
    float* out_z = out_grid + (size_t)M_BATCH * NG * 2;

    dim3 grid(GT, GT, M_BATCH);   // (9, 9, 8) = 648 blocks x 256 threads
    fused_kernel<<<grid, 256, 0, stream>>>(xc, yc, xt, lsp, out_grid, out_z);
}